// Round 13
// baseline (207.581 us; speedup 1.0000x reference)
//
#include <hip/hip_runtime.h>

// MultiHeadSelfAttention: B=2, S=2048, D=1024, H=16, Dh=64, fp32 in/out.
// R12: attn REVERTED verbatim to R10 (two rounds of LDS-free direct-load attn
// failed correctness despite three algebraic re-derivations — shelved).
// New: qkv Q/K paths retiled 128ch x 64tok (BK=64 swizzled core, 24KB LDS),
// grid (8,64,3)=1536 blocks (~5/CU vs 3). V path (z==2) byte-identical to
// R10 (128x128 + LDS transpose); its by>=32 blocks exit early.

#define T_TOK 4096
#define DM    1024
#define SQ    2048
#define NH    16
#define DH    64

typedef unsigned short u16;
typedef unsigned int   u32;
typedef __bf16 bf16x8 __attribute__((ext_vector_type(8)));
typedef float  f32x4  __attribute__((ext_vector_type(4)));
typedef float  f32x16 __attribute__((ext_vector_type(16)));
typedef u32    u32x4  __attribute__((ext_vector_type(4)));

__device__ __forceinline__ u16 f2bf(float f) {   // RNE fp32->bf16
  u32 u = __builtin_bit_cast(u32, f);
  u32 r = (u + 0x7FFFu + ((u >> 16) & 1u)) >> 16;
  return (u16)r;
}

#if __has_builtin(__builtin_amdgcn_cvt_pk_bf16_f32)
typedef __bf16 bf16x2 __attribute__((ext_vector_type(2)));
__device__ __forceinline__ u32 pk2bf(float a, float b) {
  bf16x2 h = __builtin_amdgcn_cvt_pk_bf16_f32(a, b);
  return __builtin_bit_cast(u32, h);
}
#else
__device__ __forceinline__ u32 pk2bf(float a, float b) {  // 1 instr on gfx950
  u32 r;
  asm("v_cvt_pk_bf16_f32 %0, %1, %2" : "=v"(r) : "v"(a), "v"(b));
  return r;
}
#endif

__device__ __forceinline__ void gld16(const void* g, void* l) {
  __builtin_amdgcn_global_load_lds(
      (const __attribute__((address_space(1))) u32*)g,
      (__attribute__((address_space(3))) u32*)l, 16, 0, 0);
}

// ---------------- k1: cast to bf16 ----------------
__global__ void cast_bf16_kernel(const float* __restrict__ x,
    const float* __restrict__ w0, const float* __restrict__ w1,
    const float* __restrict__ w2, const float* __restrict__ w3,
    u16* __restrict__ xb, u16* __restrict__ o0, u16* __restrict__ o1,
    u16* __restrict__ o2, u16* __restrict__ o3)
{
  const float* src; u16* dst; int n;
  switch (blockIdx.y) {
    case 0:  src = x;  dst = xb; n = T_TOK * DM; break;
    case 1:  src = w0; dst = o0; n = DM * DM; break;
    case 2:  src = w1; dst = o1; n = DM * DM; break;
    case 3:  src = w2; dst = o2; n = DM * DM; break;
    default: src = w3; dst = o3; n = DM * DM; break;
  }
  const int stride = gridDim.x * blockDim.x;
  for (int i = blockIdx.x * blockDim.x + threadIdx.x; i * 4 < n; i += stride) {
    float4 v = ((const float4*)src)[i];
    ushort4 o;
    o.x = f2bf(v.x); o.y = f2bf(v.y); o.z = f2bf(v.z); o.w = f2bf(v.w);
    ((ushort4*)dst)[i] = o;
  }
}

// ------------- shared 128x128 NT-GEMM core (K=1024, BK=64, swizzled) ---------
__device__ __forceinline__ void gemm_core_128x128(
    u16* lds, const u16* __restrict__ Ab, const u16* __restrict__ Bb,
    f32x4 acc[4][4])
{
  u16* As = lds;
  u16* Bs = lds + 8192;
  const int tid = threadIdx.x, lane = tid & 63, w = tid >> 6;
  const int waveM = w >> 1, waveN = w & 1;
  const int col = lane & 15, quad = lane >> 4;
  const int srow = lane >> 3;                  // 0..7
  const int sg0  = (lane & 7) ^ srow;          // swizzle, rb-part added below

  for (int k0 = 0; k0 < DM; k0 += 64) {
    #pragma unroll
    for (int i = 0; i < 4; ++i) {
      const int rb = w * 32 + i * 8;
      const int sg = sg0 ^ ((rb >> 3) & 3);
      gld16(Ab + (size_t)(rb + srow) * DM + k0 + sg * 8, &As[rb * 64]);
      gld16(Bb + (size_t)(rb + srow) * DM + k0 + sg * 8, &Bs[rb * 64]);
    }
    __syncthreads();
    #pragma unroll
    for (int c = 0; c < 2; ++c) {
      bf16x8 af[4], bg[4];
      #pragma unroll
      for (int i = 0; i < 4; ++i) {
        const int row = waveM * 64 + i * 16 + col;
        const int gp = (c * 4 + quad) ^ (row & 7) ^ ((row >> 3) & 3);
        af[i] = *(const bf16x8*)&As[row * 64 + gp * 8];
      }
      #pragma unroll
      for (int j = 0; j < 4; ++j) {
        const int row = waveN * 64 + j * 16 + col;
        const int gp = (c * 4 + quad) ^ (row & 7) ^ ((row >> 3) & 3);
        bg[j] = *(const bf16x8*)&Bs[row * 64 + gp * 8];
      }
      #pragma unroll
      for (int i = 0; i < 4; ++i) {
        #pragma unroll
        for (int j = 0; j < 4; ++j)
          acc[i][j] = __builtin_amdgcn_mfma_f32_16x16x32_bf16(af[i], bg[j], acc[i][j], 0, 0, 0);
      }
    }
    __syncthreads();
  }
}

// ------------- 128x64 NT-GEMM core (A=128 rows, B=64 rows, BK=64) ------------
__device__ __forceinline__ void gemm_core_128x64(
    u16* lds, const u16* __restrict__ Ab, const u16* __restrict__ Bb,
    f32x4 acc[4][2])
{
  u16* As = lds;            // [128][64]
  u16* Bs = lds + 8192;     // [64][64]
  const int tid = threadIdx.x, lane = tid & 63, w = tid >> 6;
  const int waveM = w >> 1, waveN = w & 1;
  const int col = lane & 15, quad = lane >> 4;
  const int srow = lane >> 3;
  const int sg0  = (lane & 7) ^ srow;

  for (int k0 = 0; k0 < DM; k0 += 64) {
    #pragma unroll
    for (int i = 0; i < 4; ++i) {
      const int rb = w * 32 + i * 8;
      const int sg = sg0 ^ ((rb >> 3) & 3);
      gld16(Ab + (size_t)(rb + srow) * DM + k0 + sg * 8, &As[rb * 64]);
    }
    #pragma unroll
    for (int i = 0; i < 2; ++i) {
      const int rb = w * 16 + i * 8;
      const int sg = sg0 ^ ((rb >> 3) & 3);
      gld16(Bb + (size_t)(rb + srow) * DM + k0 + sg * 8, &Bs[rb * 64]);
    }
    __syncthreads();
    #pragma unroll
    for (int c = 0; c < 2; ++c) {
      bf16x8 af[4], bg[2];
      #pragma unroll
      for (int i = 0; i < 4; ++i) {
        const int row = waveM * 64 + i * 16 + col;
        const int gp = (c * 4 + quad) ^ (row & 7) ^ ((row >> 3) & 3);
        af[i] = *(const bf16x8*)&As[row * 64 + gp * 8];
      }
      #pragma unroll
      for (int j = 0; j < 2; ++j) {
        const int row = waveN * 32 + j * 16 + col;
        const int gp = (c * 4 + quad) ^ (row & 7) ^ ((row >> 3) & 3);
        bg[j] = *(const bf16x8*)&Bs[row * 64 + gp * 8];
      }
      #pragma unroll
      for (int i = 0; i < 4; ++i) {
        #pragma unroll
        for (int j = 0; j < 2; ++j)
          acc[i][j] = __builtin_amdgcn_mfma_f32_16x16x32_bf16(af[i], bg[j], acc[i][j], 0, 0, 0);
      }
    }
    __syncthreads();
  }
}

// ---------------- k2: fused QKV projection ----------------
// z<2 (Q/K): operand-swapped 128ch x 64tok core (A=W, B=x) -> lane holds 4
//            consecutive d for one token -> direct ushort4 stores; grid y<64.
// z==2 (V):  unchanged R10 path: 128x128 core + LDS transpose; grid y<32
//            (y>=32 blocks exit).
__global__ __launch_bounds__(256) void gemm_qkv_kernel(
    const u16* __restrict__ xb,
    const u16* __restrict__ Wqb, const u16* __restrict__ Wkb, const u16* __restrict__ Wvb,
    const float* __restrict__ bq, const float* __restrict__ bk, const float* __restrict__ bv,
    u16* __restrict__ Qs, u16* __restrict__ Kh, u16* __restrict__ Vt)
{
  __shared__ __align__(16) u16 smem[128 * 136];  // 34 KB: As/Bs | tr (V path)
  u16* tr = smem;
  const int z = blockIdx.z;
  const u16*   Wb   = (z == 0) ? Wqb : (z == 1) ? Wkb : Wvb;
  const float* bias = (z == 0) ? bq  : (z == 1) ? bk  : bv;
  const float scale = (z == 0) ? 0.18033688011112042f : 1.0f;  // log2(e)/8 for Q

  const int tid = threadIdx.x;
  const int lane = tid & 63, w = tid >> 6;
  const int waveM = w >> 1, waveN = w & 1;
  const int col = lane & 15, quad = lane >> 4;
  const f32x4 zf = {0.f, 0.f, 0.f, 0.f};

  if (z == 2) {
    if (blockIdx.y >= 32) return;
    f32x4 acc[4][4];
    #pragma unroll
    for (int i = 0; i < 4; ++i) {
      #pragma unroll
      for (int j = 0; j < 4; ++j) acc[i][j] = zf;
    }
    gemm_core_128x128(smem, xb + (size_t)(blockIdx.y * 128) * DM,
                      Wb + (size_t)(blockIdx.x * 128) * DM, acc);
    // core ends with __syncthreads(); As/Bs dead -> reuse as transpose tile
    #pragma unroll
    for (int j = 0; j < 4; ++j) {
      const int cl = waveN * 64 + j * 16 + col;
      const float bb = bias[blockIdx.x * 128 + cl];
      #pragma unroll
      for (int i = 0; i < 4; ++i) {
        const int tl = waveM * 64 + i * 16 + quad * 4;
        ushort4 pk;
        pk.x = f2bf(acc[i][j][0] + bb); pk.y = f2bf(acc[i][j][1] + bb);
        pk.z = f2bf(acc[i][j][2] + bb); pk.w = f2bf(acc[i][j][3] + bb);
        *(ushort4*)&tr[cl * 136 + tl] = pk;
      }
    }
    __syncthreads();
    const int t0 = blockIdx.y * 128;
    const int b = t0 >> 11, sBase = t0 & 2047;
    #pragma unroll
    for (int rep = 0; rep < 8; ++rep) {
      const int chunk = rep * 256 + tid;
      const int row = chunk >> 4, off = (chunk & 15) * 8;
      const int c = blockIdx.x * 128 + row;
      const int h = c >> 6, d = c & 63;
      uint4 v = *(const uint4*)&tr[row * 136 + off];
      *(uint4*)&Vt[((size_t)(b * NH + h) * DH + d) * SQ + sBase + off] = v;
    }
  } else {
    f32x4 acc[4][2];
    #pragma unroll
    for (int i = 0; i < 4; ++i) {
      #pragma unroll
      for (int j = 0; j < 2; ++j) acc[i][j] = zf;
    }
    gemm_core_128x64(smem, Wb + (size_t)(blockIdx.x * 128) * DM,
                     xb + (size_t)(blockIdx.y * 64) * DM, acc);
    u16* out = (z == 0) ? Qs : Kh;
    const int chBase  = blockIdx.x * 128 + waveM * 64;   // A side = channels
    const int tokBase = blockIdx.y * 64 + waveN * 32;    // B side = tokens
    #pragma unroll
    for (int i = 0; i < 4; ++i) {
      const int c0 = chBase + i * 16 + quad * 4;         // 4 consecutive d
      const int hh = c0 >> 6, d0 = c0 & 63;
      const float4 bb = *(const float4*)&bias[c0];
      #pragma unroll
      for (int j = 0; j < 2; ++j) {
        const int t = tokBase + j * 16 + col;
        const int b = t >> 11, s = t & 2047;
        ushort4 pk;
        pk.x = f2bf((acc[i][j][0] + bb.x) * scale);
        pk.y = f2bf((acc[i][j][1] + bb.y) * scale);
        pk.z = f2bf((acc[i][j][2] + bb.z) * scale);
        pk.w = f2bf((acc[i][j][3] + bb.w) * scale);
        *(ushort4*)&out[((size_t)(b * NH + hh) * SQ + s) * DH + d0] = pk;
      }
    }
  }
}

// ---------------- k4: flash attention, 32x32x16 MFMA, double-buffered --------
// (verbatim R10 — known good) grid (S/64, B*H); block 256 = 4 waves.
__global__ __launch_bounds__(256, 2) void attn_kernel(
    const u16* __restrict__ Qs, const u16* __restrict__ Kh,
    const u16* __restrict__ Vt, u16* __restrict__ ctx)
{
  __shared__ __align__(16) char smem[64 * 1024];
  u16* KtB = (u16*)smem;                    // 2 x [128][64] swz, 8192 u16 each
  u16* VlB = (u16*)(smem + 32768);          // 2 x [64][128] swz, 8192 u16 each
  f32x4* red  = (f32x4*)smem;               // 32 KB, reused after kt loop
  float* lred = (float*)(smem + 32768);     // 1 KB, reused after kt loop

  const int tid = threadIdx.x, lane = tid & 63, w = tid >> 6;
  const int l31 = lane & 31, h = lane >> 5;
  const int bh = blockIdx.y, q0 = blockIdx.x * 64;
  const u16* Qb = Qs + ((size_t)bh * SQ + q0) * DH;
  const u16* Kb = Kh + (size_t)bh * SQ * DH;
  const u16* Vb = Vt + (size_t)bh * DH * SQ;

  bf16x8 qreg[2][4];
  #pragma unroll
  for (int qt = 0; qt < 2; ++qt) {
    #pragma unroll
    for (int ks = 0; ks < 4; ++ks)
      qreg[qt][ks] = *(const bf16x8*)(Qb + (size_t)(qt * 32 + l31) * DH
                                         + ks * 16 + h * 8);
  }

  #pragma unroll
  for (int i = 0; i < 4; ++i) {
    const int rb = w * 32 + i * 8;
    const int rowloc = rb + (lane >> 3);
    const int sg = (lane & 7) ^ (lane >> 3) ^ ((rb >> 3) & 3);
    gld16(Kb + (size_t)rowloc * DH + sg * 8, &KtB[rb * 64]);
  }
  #pragma unroll
  for (int i = 0; i < 4; ++i) {
    const int rb = w * 16 + i * 4;
    const int rowloc = rb + (lane >> 4);
    const int sg = (lane & 15) ^ (rowloc & 15);
    gld16(Vb + (size_t)rowloc * SQ + sg * 8, &VlB[rb * 128]);
  }

  f32x16 cacc[2][2];
  #pragma unroll
  for (int dt = 0; dt < 2; ++dt)
    #pragma unroll
    for (int qt = 0; qt < 2; ++qt)
      #pragma unroll
      for (int e = 0; e < 16; ++e) cacc[dt][qt][e] = 0.f;
  float l_s[2] = {0.f, 0.f};
  __syncthreads();

  for (int kt = 0; kt < SQ / 128; ++kt) {
    const int cur = kt & 1;
    u16* Kt = KtB + cur * 8192;
    u16* Vl = VlB + cur * 8192;
    if (kt + 1 < SQ / 128) {
      const int nxt = cur ^ 1, s1 = (kt + 1) * 128;
      u16* Ktn = KtB + nxt * 8192;
      u16* Vln = VlB + nxt * 8192;
      #pragma unroll
      for (int i = 0; i < 4; ++i) {
        const int rb = w * 32 + i * 8;
        const int rowloc = rb + (lane >> 3);
        const int sg = (lane & 7) ^ (lane >> 3) ^ ((rb >> 3) & 3);
        gld16(Kb + (size_t)(s1 + rowloc) * DH + sg * 8, &Ktn[rb * 64]);
      }
      #pragma unroll
      for (int i = 0; i < 4; ++i) {
        const int rb = w * 16 + i * 4;
        const int rowloc = rb + (lane >> 4);
        const int sg = (lane & 15) ^ (rowloc & 15);
        gld16(Vb + (size_t)rowloc * SQ + s1 + sg * 8, &Vln[rb * 128]);
      }
    }

    f32x16 sacc[2];
    #pragma unroll
    for (int qt = 0; qt < 2; ++qt)
      #pragma unroll
      for (int e = 0; e < 16; ++e) sacc[qt][e] = 0.f;
    #pragma unroll
    for (int ks = 0; ks < 4; ++ks) {
      const int row = w * 32 + l31;
      const int gp = (2 * ks + h) ^ (l31 & 7) ^ ((l31 >> 3) & 3);
      bf16x8 kf = *(const bf16x8*)&Kt[row * 64 + gp * 8];
      sacc[0] = __builtin_amdgcn_mfma_f32_32x32x16_bf16(kf, qreg[0][ks], sacc[0], 0, 0, 0);
      sacc[1] = __builtin_amdgcn_mfma_f32_32x32x16_bf16(kf, qreg[1][ks], sacc[1], 0, 0, 0);
    }

    u32 Pp[2][4][2];
    #pragma unroll
    for (int qt = 0; qt < 2; ++qt) {
      float p[16];
      #pragma unroll
      for (int e = 0; e < 16; ++e)
        p[e] = __builtin_amdgcn_exp2f(sacc[qt][e]);
      float t0 = (p[0] + p[1]) + (p[2] + p[3]);
      float t1 = (p[4] + p[5]) + (p[6] + p[7]);
      float t2 = (p[8] + p[9]) + (p[10] + p[11]);
      float t3 = (p[12] + p[13]) + (p[14] + p[15]);
      l_s[qt] += (t0 + t1) + (t2 + t3);
      #pragma unroll
      for (int rg = 0; rg < 4; ++rg) {
        Pp[qt][rg][0] = pk2bf(p[4 * rg + 0], p[4 * rg + 1]);
        Pp[qt][rg][1] = pk2bf(p[4 * rg + 2], p[4 * rg + 3]);
      }
    }

    #pragma unroll
    for (int ks = 0; ks < 2; ++ks) {
      bf16x8 pf[2];
      #pragma unroll
      for (int qt = 0; qt < 2; ++qt) {
        u32 own0 = h ? Pp[qt][2 * ks + 1][0] : Pp[qt][2 * ks][0];
        u32 own1 = h ? Pp[qt][2 * ks + 1][1] : Pp[qt][2 * ks][1];
        u32 snd0 = h ? Pp[qt][2 * ks][0] : Pp[qt][2 * ks + 1][0];
        u32 snd1 = h ? Pp[qt][2 * ks][1] : Pp[qt][2 * ks + 1][1];
        u32 rcv0 = (u32)__shfl_xor((int)snd0, 32, 64);
        u32 rcv1 = (u32)__shfl_xor((int)snd1, 32, 64);
        u32x4 fw;
        fw.x = h ? rcv0 : own0;
        fw.y = h ? rcv1 : own1;
        fw.z = h ? own0 : rcv0;
        fw.w = h ? own1 : rcv1;
        pf[qt] = __builtin_bit_cast(bf16x8, fw);
      }
      #pragma unroll
      for (int dt = 0; dt < 2; ++dt) {
        const int row = dt * 32 + l31;
        const int gp = (4 * w + 2 * ks + h) ^ (row & 15);
        bf16x8 vf = *(const bf16x8*)&Vl[row * 128 + gp * 8];
        cacc[dt][0] = __builtin_amdgcn_mfma_f32_32x32x16_bf16(vf, pf[0], cacc[dt][0], 0, 0, 0);
        cacc[dt][1] = __builtin_amdgcn_mfma_f32_32x32x16_bf16(vf, pf[1], cacc[dt][1], 0, 0, 0);
      }
    }
    __syncthreads();
  }

  float lq[2];
  #pragma unroll
  for (int qt = 0; qt < 2; ++qt) {
    lq[qt] = l_s[qt] + __shfl_xor(l_s[qt], 32, 64);
    if (h == 0) lred[(w * 2 + qt) * 32 + l31] = lq[qt];
  }
  const int b = bh >> 4, hd = bh & 15;
  #pragma unroll
  for (int qt = 0; qt < 2; ++qt) {
    __syncthreads();
    #pragma unroll
    for (int dt = 0; dt < 2; ++dt) {
      #pragma unroll
      for (int c = 0; c < 4; ++c) {
        f32x4 ch;
        ch[0] = cacc[dt][qt][4 * c + 0]; ch[1] = cacc[dt][qt][4 * c + 1];
        ch[2] = cacc[dt][qt][4 * c + 2]; ch[3] = cacc[dt][qt][4 * c + 3];
        red[((w * 2 + dt) * 4 + c) * 64 + lane] = ch;
      }
    }
    __syncthreads();
    const int dt = w >> 1, c0 = (w & 1) * 2;
    f32x4 sum[2];
    #pragma unroll
    for (int j = 0; j < 2; ++j) { sum[j][0]=0; sum[j][1]=0; sum[j][2]=0; sum[j][3]=0; }
    #pragma unroll
    for (int sw = 0; sw < 4; ++sw) {
      #pragma unroll
      for (int j = 0; j < 2; ++j)
        sum[j] += red[((sw * 2 + dt) * 4 + c0 + j) * 64 + lane];
    }
    float lsum = lred[(0 * 2 + qt) * 32 + l31] + lred[(1 * 2 + qt) * 32 + l31]
               + lred[(2 * 2 + qt) * 32 + l31] + lred[(3 * 2 + qt) * 32 + l31];
    const float inv = 1.0f / lsum;
    const int s = q0 + qt * 32 + l31;
    #pragma unroll
    for (int j = 0; j < 2; ++j) {
      const int d0 = dt * 32 + (c0 + j) * 8 + 4 * h;
      ushort4 pk;
      pk.x = f2bf(sum[j][0] * inv); pk.y = f2bf(sum[j][1] * inv);
      pk.z = f2bf(sum[j][2] * inv); pk.w = f2bf(sum[j][3] * inv);
      *(ushort4*)&ctx[(size_t)(b * SQ + s) * DM + hd * DH + d0] = pk;
    }
  }
}

// -------- k5: output projection (64x64 tiles, BK=64 swizzled, fp32 out) ------
__global__ __launch_bounds__(256) void gemm_out_kernel(
    const u16* __restrict__ ctx, const u16* __restrict__ Wob,
    const float* __restrict__ bo, float* __restrict__ out)
{
  __shared__ __align__(16) u16 As[64 * 64];
  __shared__ __align__(16) u16 Bs[64 * 64];
  const u16* Ab = ctx + (size_t)(blockIdx.y * 64) * DM;
  const u16* Bb = Wob + (size_t)(blockIdx.x * 64) * DM;
  const int tid = threadIdx.x, lane = tid & 63, w = tid >> 6;
  const int waveM = w >> 1, waveN = w & 1;
  const int col = lane & 15, quad = lane >> 4;
  const int srow = lane >> 3;
  const int sg0  = (lane & 7) ^ srow;

  f32x4 acc[2][2];
  const f32x4 zf = {0.f, 0.f, 0.f, 0.f};
  #pragma unroll
  for (int i = 0; i < 2; ++i) {
    #pragma unroll
    for (int j = 0; j < 2; ++j) acc[i][j] = zf;
  }

  for (int k0 = 0; k0 < DM; k0 += 64) {
    #pragma unroll
    for (int i = 0; i < 2; ++i) {
      const int rb = w * 16 + i * 8;
      const int sg = sg0 ^ ((rb >> 3) & 3);
      gld16(Ab + (size_t)(rb + srow) * DM + k0 + sg * 8, &As[rb * 64]);
      gld16(Bb + (size_t)(rb + srow) * DM + k0 + sg * 8, &Bs[rb * 64]);
    }
    __syncthreads();
    #pragma unroll
    for (int c = 0; c < 2; ++c) {
      bf16x8 af[2], bg[2];
      #pragma unroll
      for (int i = 0; i < 2; ++i) {
        const int row = waveM * 32 + i * 16 + col;
        const int gp = (c * 4 + quad) ^ (row & 7) ^ ((row >> 3) & 3);
        af[i] = *(const bf16x8*)&As[row * 64 + gp * 8];
      }
      #pragma unroll
      for (int j = 0; j < 2; ++j) {
        const int row = waveN * 32 + j * 16 + col;
        const int gp = (c * 4 + quad) ^ (row & 7) ^ ((row >> 3) & 3);
        bg[j] = *(const bf16x8*)&Bs[row * 64 + gp * 8];
      }
      #pragma unroll
      for (int i = 0; i < 2; ++i) {
        #pragma unroll
        for (int j = 0; j < 2; ++j)
          acc[i][j] = __builtin_amdgcn_mfma_f32_16x16x32_bf16(af[i], bg[j], acc[i][j], 0, 0, 0);
      }
    }
    __syncthreads();
  }

  const int rowBase = blockIdx.y * 64 + waveM * 32;
  const int colBase = blockIdx.x * 64 + waveN * 32;
  #pragma unroll
  for (int j = 0; j < 2; ++j) {
    const int c = colBase + j * 16 + col;
    const float bb = bo[c];
    #pragma unroll
    for (int i = 0; i < 2; ++i) {
      #pragma unroll
      for (int r = 0; r < 4; ++r) {
        const int t = rowBase + i * 16 + quad * 4 + r;
        out[(size_t)t * DM + c] = acc[i][j][r] + bb;
      }
    }
  }
}

extern "C" void kernel_launch(void* const* d_in, const int* in_sizes, int n_in,
                              void* d_out, int out_size, void* d_ws, size_t ws_size,
                              hipStream_t stream) {
  const float* x  = (const float*)d_in[0];
  const float* Wq = (const float*)d_in[1];
  const float* bq = (const float*)d_in[2];
  const float* Wk = (const float*)d_in[3];
  const float* bk = (const float*)d_in[4];
  const float* Wv = (const float*)d_in[5];
  const float* bv = (const float*)d_in[6];
  const float* Wo = (const float*)d_in[7];
  const float* bo = (const float*)d_in[8];

  char* ws = (char*)d_ws;                  // 40 MB used
  u16* xb  = (u16*)(ws);                   // 8 MB  (reused as ctx after QKV)
  u16* Wqb = (u16*)(ws + (8ull  << 20));   // 2 MB
  u16* Wkb = (u16*)(ws + (10ull << 20));   // 2 MB
  u16* Wvb = (u16*)(ws + (12ull << 20));   // 2 MB
  u16* Wob = (u16*)(ws + (14ull << 20));   // 2 MB
  u16* Qs  = (u16*)(ws + (16ull << 20));   // 8 MB  [b,h,s,d], pre-scaled
  u16* Kh  = (u16*)(ws + (24ull << 20));   // 8 MB  [b,h,s,d]
  u16* Vt  = (u16*)(ws + (32ull << 20));   // 8 MB  [b,h,d,s]
  u16* ctx = xb;                           // alias: xb dead after QKV GEMM

  cast_bf16_kernel<<<dim3(256, 5), 256, 0, stream>>>(x, Wq, Wk, Wv, Wo,
                                                     xb, Wqb, Wkb, Wvb, Wob);
  gemm_qkv_kernel<<<dim3(8, 64, 3), 256, 0, stream>>>(xb, Wqb, Wkb, Wvb,
                                                      bq, bk, bv, Qs, Kh, Vt);
  attn_kernel<<<dim3(32, 32), 256, 0, stream>>>(Qs, Kh, Vt, ctx);
  gemm_out_kernel<<<dim3(16, 64), 256, 0, stream>>>(ctx, Wob, bo, (float*)d_out);
  (void)in_sizes; (void)n_in; (void)out_size; (void)ws_size;
}

// Round 14
// 205.434 us; speedup vs baseline: 1.0104x; 1.0104x over previous
//
#include <hip/hip_runtime.h>

// MultiHeadSelfAttention: B=2, S=2048, D=1024, H=16, Dh=64, fp32 in/out.
// R14: attn kt-tile 64, wave = (q-half, s'-half): 32KB LDS -> 4 blocks/CU
// (was 2) to hide the per-iter vmcnt(0)+barrier drain via cross-block
// overlap (m114). Same 32x32 dataflow/layouts as R10; cacc halves to 32
// VGPR; epilogue reduction = one barrier, 2-source sums. Vl pitch 64 is
// bank-safe: XOR key has (row>>3)&3 -> each 16-lane b128 phase is 2-way.
// GEMMs/cast verbatim R13.

#define T_TOK 4096
#define DM    1024
#define SQ    2048
#define NH    16
#define DH    64

typedef unsigned short u16;
typedef unsigned int   u32;
typedef __bf16 bf16x8 __attribute__((ext_vector_type(8)));
typedef float  f32x4  __attribute__((ext_vector_type(4)));
typedef float  f32x16 __attribute__((ext_vector_type(16)));
typedef u32    u32x4  __attribute__((ext_vector_type(4)));

__device__ __forceinline__ u16 f2bf(float f) {   // RNE fp32->bf16
  u32 u = __builtin_bit_cast(u32, f);
  u32 r = (u + 0x7FFFu + ((u >> 16) & 1u)) >> 16;
  return (u16)r;
}

#if __has_builtin(__builtin_amdgcn_cvt_pk_bf16_f32)
typedef __bf16 bf16x2 __attribute__((ext_vector_type(2)));
__device__ __forceinline__ u32 pk2bf(float a, float b) {
  bf16x2 h = __builtin_amdgcn_cvt_pk_bf16_f32(a, b);
  return __builtin_bit_cast(u32, h);
}
#else
__device__ __forceinline__ u32 pk2bf(float a, float b) {  // 1 instr on gfx950
  u32 r;
  asm("v_cvt_pk_bf16_f32 %0, %1, %2" : "=v"(r) : "v"(a), "v"(b));
  return r;
}
#endif

__device__ __forceinline__ void gld16(const void* g, void* l) {
  __builtin_amdgcn_global_load_lds(
      (const __attribute__((address_space(1))) u32*)g,
      (__attribute__((address_space(3))) u32*)l, 16, 0, 0);
}

// ---------------- k1: cast to bf16 ----------------
__global__ void cast_bf16_kernel(const float* __restrict__ x,
    const float* __restrict__ w0, const float* __restrict__ w1,
    const float* __restrict__ w2, const float* __restrict__ w3,
    u16* __restrict__ xb, u16* __restrict__ o0, u16* __restrict__ o1,
    u16* __restrict__ o2, u16* __restrict__ o3)
{
  const float* src; u16* dst; int n;
  switch (blockIdx.y) {
    case 0:  src = x;  dst = xb; n = T_TOK * DM; break;
    case 1:  src = w0; dst = o0; n = DM * DM; break;
    case 2:  src = w1; dst = o1; n = DM * DM; break;
    case 3:  src = w2; dst = o2; n = DM * DM; break;
    default: src = w3; dst = o3; n = DM * DM; break;
  }
  const int stride = gridDim.x * blockDim.x;
  for (int i = blockIdx.x * blockDim.x + threadIdx.x; i * 4 < n; i += stride) {
    float4 v = ((const float4*)src)[i];
    ushort4 o;
    o.x = f2bf(v.x); o.y = f2bf(v.y); o.z = f2bf(v.z); o.w = f2bf(v.w);
    ((ushort4*)dst)[i] = o;
  }
}

// ------------- shared 128x128 NT-GEMM core (K=1024, BK=64, swizzled) ---------
__device__ __forceinline__ void gemm_core_128x128(
    u16* lds, const u16* __restrict__ Ab, const u16* __restrict__ Bb,
    f32x4 acc[4][4])
{
  u16* As = lds;
  u16* Bs = lds + 8192;
  const int tid = threadIdx.x, lane = tid & 63, w = tid >> 6;
  const int waveM = w >> 1, waveN = w & 1;
  const int col = lane & 15, quad = lane >> 4;
  const int srow = lane >> 3;                  // 0..7
  const int sg0  = (lane & 7) ^ srow;          // swizzle, rb-part added below

  for (int k0 = 0; k0 < DM; k0 += 64) {
    #pragma unroll
    for (int i = 0; i < 4; ++i) {
      const int rb = w * 32 + i * 8;
      const int sg = sg0 ^ ((rb >> 3) & 3);
      gld16(Ab + (size_t)(rb + srow) * DM + k0 + sg * 8, &As[rb * 64]);
      gld16(Bb + (size_t)(rb + srow) * DM + k0 + sg * 8, &Bs[rb * 64]);
    }
    __syncthreads();
    #pragma unroll
    for (int c = 0; c < 2; ++c) {
      bf16x8 af[4], bg[4];
      #pragma unroll
      for (int i = 0; i < 4; ++i) {
        const int row = waveM * 64 + i * 16 + col;
        const int gp = (c * 4 + quad) ^ (row & 7) ^ ((row >> 3) & 3);
        af[i] = *(const bf16x8*)&As[row * 64 + gp * 8];
      }
      #pragma unroll
      for (int j = 0; j < 4; ++j) {
        const int row = waveN * 64 + j * 16 + col;
        const int gp = (c * 4 + quad) ^ (row & 7) ^ ((row >> 3) & 3);
        bg[j] = *(const bf16x8*)&Bs[row * 64 + gp * 8];
      }
      #pragma unroll
      for (int i = 0; i < 4; ++i) {
        #pragma unroll
        for (int j = 0; j < 4; ++j)
          acc[i][j] = __builtin_amdgcn_mfma_f32_16x16x32_bf16(af[i], bg[j], acc[i][j], 0, 0, 0);
      }
    }
    __syncthreads();
  }
}

// ------------- 128x64 NT-GEMM core (A=128 rows, B=64 rows, BK=64) ------------
__device__ __forceinline__ void gemm_core_128x64(
    u16* lds, const u16* __restrict__ Ab, const u16* __restrict__ Bb,
    f32x4 acc[4][2])
{
  u16* As = lds;            // [128][64]
  u16* Bs = lds + 8192;     // [64][64]
  const int tid = threadIdx.x, lane = tid & 63, w = tid >> 6;
  const int waveM = w >> 1, waveN = w & 1;
  const int col = lane & 15, quad = lane >> 4;
  const int srow = lane >> 3;
  const int sg0  = (lane & 7) ^ srow;

  for (int k0 = 0; k0 < DM; k0 += 64) {
    #pragma unroll
    for (int i = 0; i < 4; ++i) {
      const int rb = w * 32 + i * 8;
      const int sg = sg0 ^ ((rb >> 3) & 3);
      gld16(Ab + (size_t)(rb + srow) * DM + k0 + sg * 8, &As[rb * 64]);
    }
    #pragma unroll
    for (int i = 0; i < 2; ++i) {
      const int rb = w * 16 + i * 8;
      const int sg = sg0 ^ ((rb >> 3) & 3);
      gld16(Bb + (size_t)(rb + srow) * DM + k0 + sg * 8, &Bs[rb * 64]);
    }
    __syncthreads();
    #pragma unroll
    for (int c = 0; c < 2; ++c) {
      bf16x8 af[4], bg[2];
      #pragma unroll
      for (int i = 0; i < 4; ++i) {
        const int row = waveM * 64 + i * 16 + col;
        const int gp = (c * 4 + quad) ^ (row & 7) ^ ((row >> 3) & 3);
        af[i] = *(const bf16x8*)&As[row * 64 + gp * 8];
      }
      #pragma unroll
      for (int j = 0; j < 2; ++j) {
        const int row = waveN * 32 + j * 16 + col;
        const int gp = (c * 4 + quad) ^ (row & 7) ^ ((row >> 3) & 3);
        bg[j] = *(const bf16x8*)&Bs[row * 64 + gp * 8];
      }
      #pragma unroll
      for (int i = 0; i < 4; ++i) {
        #pragma unroll
        for (int j = 0; j < 2; ++j)
          acc[i][j] = __builtin_amdgcn_mfma_f32_16x16x32_bf16(af[i], bg[j], acc[i][j], 0, 0, 0);
      }
    }
    __syncthreads();
  }
}

// ---------------- k2: fused QKV projection ----------------
__global__ __launch_bounds__(256) void gemm_qkv_kernel(
    const u16* __restrict__ xb,
    const u16* __restrict__ Wqb, const u16* __restrict__ Wkb, const u16* __restrict__ Wvb,
    const float* __restrict__ bq, const float* __restrict__ bk, const float* __restrict__ bv,
    u16* __restrict__ Qs, u16* __restrict__ Kh, u16* __restrict__ Vt)
{
  __shared__ __align__(16) u16 smem[128 * 136];  // 34 KB: As/Bs | tr (V path)
  u16* tr = smem;
  const int z = blockIdx.z;
  const u16*   Wb   = (z == 0) ? Wqb : (z == 1) ? Wkb : Wvb;
  const float* bias = (z == 0) ? bq  : (z == 1) ? bk  : bv;
  const float scale = (z == 0) ? 0.18033688011112042f : 1.0f;  // log2(e)/8 for Q

  const int tid = threadIdx.x;
  const int lane = tid & 63, w = tid >> 6;
  const int waveM = w >> 1, waveN = w & 1;
  const int col = lane & 15, quad = lane >> 4;
  const f32x4 zf = {0.f, 0.f, 0.f, 0.f};

  if (z == 2) {
    if (blockIdx.y >= 32) return;
    f32x4 acc[4][4];
    #pragma unroll
    for (int i = 0; i < 4; ++i) {
      #pragma unroll
      for (int j = 0; j < 4; ++j) acc[i][j] = zf;
    }
    gemm_core_128x128(smem, xb + (size_t)(blockIdx.y * 128) * DM,
                      Wb + (size_t)(blockIdx.x * 128) * DM, acc);
    // core ends with __syncthreads(); As/Bs dead -> reuse as transpose tile
    #pragma unroll
    for (int j = 0; j < 4; ++j) {
      const int cl = waveN * 64 + j * 16 + col;
      const float bb = bias[blockIdx.x * 128 + cl];
      #pragma unroll
      for (int i = 0; i < 4; ++i) {
        const int tl = waveM * 64 + i * 16 + quad * 4;
        ushort4 pk;
        pk.x = f2bf(acc[i][j][0] + bb); pk.y = f2bf(acc[i][j][1] + bb);
        pk.z = f2bf(acc[i][j][2] + bb); pk.w = f2bf(acc[i][j][3] + bb);
        *(ushort4*)&tr[cl * 136 + tl] = pk;
      }
    }
    __syncthreads();
    const int t0 = blockIdx.y * 128;
    const int b = t0 >> 11, sBase = t0 & 2047;
    #pragma unroll
    for (int rep = 0; rep < 8; ++rep) {
      const int chunk = rep * 256 + tid;
      const int row = chunk >> 4, off = (chunk & 15) * 8;
      const int c = blockIdx.x * 128 + row;
      const int h = c >> 6, d = c & 63;
      uint4 v = *(const uint4*)&tr[row * 136 + off];
      *(uint4*)&Vt[((size_t)(b * NH + h) * DH + d) * SQ + sBase + off] = v;
    }
  } else {
    f32x4 acc[4][2];
    #pragma unroll
    for (int i = 0; i < 4; ++i) {
      #pragma unroll
      for (int j = 0; j < 2; ++j) acc[i][j] = zf;
    }
    gemm_core_128x64(smem, Wb + (size_t)(blockIdx.x * 128) * DM,
                     xb + (size_t)(blockIdx.y * 64) * DM, acc);
    u16* out = (z == 0) ? Qs : Kh;
    const int chBase  = blockIdx.x * 128 + waveM * 64;   // A side = channels
    const int tokBase = blockIdx.y * 64 + waveN * 32;    // B side = tokens
    #pragma unroll
    for (int i = 0; i < 4; ++i) {
      const int c0 = chBase + i * 16 + quad * 4;         // 4 consecutive d
      const int hh = c0 >> 6, d0 = c0 & 63;
      const float4 bb = *(const float4*)&bias[c0];
      #pragma unroll
      for (int j = 0; j < 2; ++j) {
        const int t = tokBase + j * 16 + col;
        const int b = t >> 11, s = t & 2047;
        ushort4 pk;
        pk.x = f2bf((acc[i][j][0] + bb.x) * scale);
        pk.y = f2bf((acc[i][j][1] + bb.y) * scale);
        pk.z = f2bf((acc[i][j][2] + bb.z) * scale);
        pk.w = f2bf((acc[i][j][3] + bb.w) * scale);
        *(ushort4*)&out[((size_t)(b * NH + hh) * SQ + s) * DH + d0] = pk;
      }
    }
  }
}

// ---------------- k4: flash attention, 32x32x16 MFMA, kt-tile 64 -------------
// grid (S/64, B*H); block 256 = 4 waves. Wave w: qt = w&1 (q-half),
// st = w>>1 (s'-half). Per iter: S^T(32s' x 32q) = K*Q^T (4 MFMA),
// p = exp2(s), P in regs (C->B via shfl_xor(32)), ctx^T partial (64d x 32q,
// 2 MFMA x 2 ks). K/V double-buffered 8KB tiles (32KB total) -> 4 blocks/CU.
// Swizzle key(row) = (row&7)^((row>>3)&3): each 16-lane b128 phase 2-way.
__global__ __launch_bounds__(256, 4) void attn_kernel(
    const u16* __restrict__ Qs, const u16* __restrict__ Kh,
    const u16* __restrict__ Vt, u16* __restrict__ ctx)
{
  __shared__ __align__(16) char smem[33 * 1024];
  u16* KtB = (u16*)smem;                    // 2 x [64][64] swz, 4096 u16 each
  u16* VlB = (u16*)(smem + 16384);          // 2 x [64][64] swz, 4096 u16 each
  f32x4* red  = (f32x4*)smem;               // 32 KB, reused after kt loop
  float* lred = (float*)(smem + 32768);     // 1 KB

  const int tid = threadIdx.x, lane = tid & 63, w = tid >> 6;
  const int l31 = lane & 31, h = lane >> 5;
  const int qt = w & 1, st = w >> 1;
  const int bh = blockIdx.y, q0 = blockIdx.x * 64;
  const u16* Qb = Qs + ((size_t)bh * SQ + q0) * DH;
  const u16* Kb = Kh + (size_t)bh * SQ * DH;
  const u16* Vb = Vt + (size_t)bh * DH * SQ;
  const int srow = lane >> 3;               // staging row-in-group 0..7
  const int sgl  = (lane & 7) ^ srow;       // staging swizzle, rb part below

  // Q B-frags (only this wave's q-half): n = q = q0+qt*32+l31, k = 16ks+8h+j
  bf16x8 qreg[4];
  #pragma unroll
  for (int ks = 0; ks < 4; ++ks)
    qreg[ks] = *(const bf16x8*)(Qb + (size_t)(qt * 32 + l31) * DH + ks * 16 + h * 8);

  // stage tile 0 into buffer 0 (each wave: 16 rows of K, 16 rows of V)
  #pragma unroll
  for (int i = 0; i < 2; ++i) {
    const int rb = w * 16 + i * 8;
    const int sg = sgl ^ ((rb >> 3) & 3);
    gld16(Kb + (size_t)(rb + srow) * DH + sg * 8, &KtB[rb * 64]);
    gld16(Vb + (size_t)(rb + srow) * SQ + sg * 8, &VlB[rb * 64]);
  }

  f32x16 cacc[2];                    // [dt] partial ctx^T (64d x 32q)
  #pragma unroll
  for (int dt = 0; dt < 2; ++dt)
    #pragma unroll
    for (int e = 0; e < 16; ++e) cacc[dt][e] = 0.f;
  float l_s = 0.f;
  __syncthreads();

  for (int kt = 0; kt < SQ / 64; ++kt) {
    const int cur = kt & 1;
    u16* Kt = KtB + cur * 4096;
    u16* Vl = VlB + cur * 4096;
    if (kt + 1 < SQ / 64) {                // prefetch next tile into other buf
      const int nxt = cur ^ 1, s1 = (kt + 1) * 64;
      u16* Ktn = KtB + nxt * 4096;
      u16* Vln = VlB + nxt * 4096;
      #pragma unroll
      for (int i = 0; i < 2; ++i) {
        const int rb = w * 16 + i * 8;
        const int sg = sgl ^ ((rb >> 3) & 3);
        gld16(Kb + (size_t)(s1 + rb + srow) * DH + sg * 8, &Ktn[rb * 64]);
        gld16(Vb + (size_t)(rb + srow) * SQ + s1 + sg * 8, &Vln[rb * 64]);
      }
    }

    // S^T = K Q^T over wave's 32-s' slice (rows st*32..+32)
    f32x16 sacc;
    #pragma unroll
    for (int e = 0; e < 16; ++e) sacc[e] = 0.f;
    #pragma unroll
    for (int ks = 0; ks < 4; ++ks) {
      const int row = st * 32 + l31;
      const int gp = (2 * ks + h) ^ (l31 & 7) ^ ((l31 >> 3) & 3);
      bf16x8 kf = *(const bf16x8*)&Kt[row * 64 + gp * 8];
      sacc = __builtin_amdgcn_mfma_f32_32x32x16_bf16(kf, qreg[ks], sacc, 0, 0, 0);
    }

    // softmax p = exp2(s); Pp[rg][u] covers s'loc = 8rg + 4h + 2u + {0,1}
    u32 Pp[4][2];
    {
      float p[16];
      #pragma unroll
      for (int e = 0; e < 16; ++e)
        p[e] = __builtin_amdgcn_exp2f(sacc[e]);
      float t0 = (p[0] + p[1]) + (p[2] + p[3]);
      float t1 = (p[4] + p[5]) + (p[6] + p[7]);
      float t2 = (p[8] + p[9]) + (p[10] + p[11]);
      float t3 = (p[12] + p[13]) + (p[14] + p[15]);
      l_s += (t0 + t1) + (t2 + t3);
      #pragma unroll
      for (int rg = 0; rg < 4; ++rg) {
        Pp[rg][0] = pk2bf(p[4 * rg + 0], p[4 * rg + 1]);
        Pp[rg][1] = pk2bf(p[4 * rg + 2], p[4 * rg + 3]);
      }
    }

    // ctx^T += V^T(slice) P^T(slice): 2 ksteps over the 32 s'
    #pragma unroll
    for (int ks = 0; ks < 2; ++ks) {
      u32 own0 = h ? Pp[2 * ks + 1][0] : Pp[2 * ks][0];
      u32 own1 = h ? Pp[2 * ks + 1][1] : Pp[2 * ks][1];
      u32 snd0 = h ? Pp[2 * ks][0] : Pp[2 * ks + 1][0];
      u32 snd1 = h ? Pp[2 * ks][1] : Pp[2 * ks + 1][1];
      u32 rcv0 = (u32)__shfl_xor((int)snd0, 32, 64);
      u32 rcv1 = (u32)__shfl_xor((int)snd1, 32, 64);
      u32x4 fw;
      fw.x = h ? rcv0 : own0;
      fw.y = h ? rcv1 : own1;
      fw.z = h ? own0 : rcv0;
      fw.w = h ? own1 : rcv1;
      bf16x8 pf = __builtin_bit_cast(bf16x8, fw);
      #pragma unroll
      for (int dt = 0; dt < 2; ++dt) {
        const int row = dt * 32 + l31;
        const int gp = (4 * st + 2 * ks + h) ^ (l31 & 7) ^ ((l31 >> 3) & 3);
        bf16x8 vf = *(const bf16x8*)&Vl[row * 64 + gp * 8];
        cacc[dt] = __builtin_amdgcn_mfma_f32_32x32x16_bf16(vf, pf, cacc[dt], 0, 0, 0);
      }
    }
    __syncthreads();   // buffer-swap fence + prefetch drain
  }

  // ----- cross-wave reduction (2 sources per output) + epilogue -----
  float lq = l_s + __shfl_xor(l_s, 32, 64);
  if (h == 0) lred[w * 32 + l31] = lq;
  #pragma unroll
  for (int dt = 0; dt < 2; ++dt) {
    #pragma unroll
    for (int c = 0; c < 4; ++c) {
      f32x4 ch;
      ch[0] = cacc[dt][4 * c + 0]; ch[1] = cacc[dt][4 * c + 1];
      ch[2] = cacc[dt][4 * c + 2]; ch[3] = cacc[dt][4 * c + 3];
      red[((w * 2 + dt) * 4 + c) * 64 + lane] = ch;
    }
  }
  __syncthreads();
  // wave w outputs qt' = w&1, d-slice dt' = w>>1; sources: waves qt', qt'+2
  const int qt2 = w & 1, dt2 = w >> 1;
  const int b = bh >> 4, hd = bh & 15;
  const float lsum = lred[qt2 * 32 + l31] + lred[(2 + qt2) * 32 + l31];
  const float inv = 1.0f / lsum;
  const int s = q0 + qt2 * 32 + l31;
  #pragma unroll
  for (int c = 0; c < 4; ++c) {
    f32x4 sum = red[((qt2 * 2 + dt2) * 4 + c) * 64 + lane];
    sum += red[(((2 + qt2) * 2 + dt2) * 4 + c) * 64 + lane];
    const int d0 = dt2 * 32 + c * 8 + 4 * h;
    ushort4 pk;
    pk.x = f2bf(sum[0] * inv); pk.y = f2bf(sum[1] * inv);
    pk.z = f2bf(sum[2] * inv); pk.w = f2bf(sum[3] * inv);
    *(ushort4*)&ctx[(size_t)(b * SQ + s) * DM + hd * DH + d0] = pk;
  }
}

// -------- k5: output projection (64x64 tiles, BK=64 swizzled, fp32 out) ------
__global__ __launch_bounds__(256) void gemm_out_kernel(
    const u16* __restrict__ ctx, const u16* __restrict__ Wob,
    const float* __restrict__ bo, float* __restrict__ out)
{
  __shared__ __align__(16) u16 As[64 * 64];
  __shared__ __align__(16) u16 Bs[64 * 64];
  const u16* Ab = ctx + (size_t)(blockIdx.y * 64) * DM;
  const u16* Bb = Wob + (size_t)(blockIdx.x * 64) * DM;
  const int tid = threadIdx.x, lane = tid & 63, w = tid >> 6;
  const int waveM = w >> 1, waveN = w & 1;
  const int col = lane & 15, quad = lane >> 4;
  const int srow = lane >> 3;
  const int sg0  = (lane & 7) ^ srow;

  f32x4 acc[2][2];
  const f32x4 zf = {0.f, 0.f, 0.f, 0.f};
  #pragma unroll
  for (int i = 0; i < 2; ++i) {
    #pragma unroll
    for (int j = 0; j < 2; ++j) acc[i][j] = zf;
  }

  for (int k0 = 0; k0 < DM; k0 += 64) {
    #pragma unroll
    for (int i = 0; i < 2; ++i) {
      const int rb = w * 16 + i * 8;
      const int sg = sg0 ^ ((rb >> 3) & 3);
      gld16(Ab + (size_t)(rb + srow) * DM + k0 + sg * 8, &As[rb * 64]);
      gld16(Bb + (size_t)(rb + srow) * DM + k0 + sg * 8, &Bs[rb * 64]);
    }
    __syncthreads();
    #pragma unroll
    for (int c = 0; c < 2; ++c) {
      bf16x8 af[2], bg[2];
      #pragma unroll
      for (int i = 0; i < 2; ++i) {
        const int row = waveM * 32 + i * 16 + col;
        const int gp = (c * 4 + quad) ^ (row & 7) ^ ((row >> 3) & 3);
        af[i] = *(const bf16x8*)&As[row * 64 + gp * 8];
      }
      #pragma unroll
      for (int j = 0; j < 2; ++j) {
        const int row = waveN * 32 + j * 16 + col;
        const int gp = (c * 4 + quad) ^ (row & 7) ^ ((row >> 3) & 3);
        bg[j] = *(const bf16x8*)&Bs[row * 64 + gp * 8];
      }
      #pragma unroll
      for (int i = 0; i < 2; ++i) {
        #pragma unroll
        for (int j = 0; j < 2; ++j)
          acc[i][j] = __builtin_amdgcn_mfma_f32_16x16x32_bf16(af[i], bg[j], acc[i][j], 0, 0, 0);
      }
    }
    __syncthreads();
  }

  const int rowBase = blockIdx.y * 64 + waveM * 32;
  const int colBase = blockIdx.x * 64 + waveN * 32;
  #pragma unroll
  for (int j = 0; j < 2; ++j) {
    const int c = colBase + j * 16 + col;
    const float bb = bo[c];
    #pragma unroll
    for (int i = 0; i < 2; ++i) {
      #pragma unroll
      for (int r = 0; r < 4; ++r) {
        const int t = rowBase + i * 16 + quad * 4 + r;
        out[(size_t)t * DM + c] = acc[i][j][r] + bb;
      }
    }
  }
}

extern "C" void kernel_launch(void* const* d_in, const int* in_sizes, int n_in,
                              void* d_out, int out_size, void* d_ws, size_t ws_size,
                              hipStream_t stream) {
  const float* x  = (const float*)d_in[0];
  const float* Wq = (const float*)d_in[1];
  const float* bq = (const float*)d_in[2];
  const float* Wk = (const float*)d_in[3];
  const float* bk = (const float*)d_in[4];
  const float* Wv = (const float*)d_in[5];
  const float* bv = (const float*)d_in[6];
  const float* Wo = (const float*)d_in[7];
  const float* bo = (const float*)d_in[8];

  char* ws = (char*)d_ws;                  // 40 MB used
  u16* xb  = (u16*)(ws);                   // 8 MB  (reused as ctx after QKV)
  u16* Wqb = (u16*)(ws + (8ull  << 20));   // 2 MB
  u16* Wkb = (u16*)(ws + (10ull << 20));   // 2 MB
  u16* Wvb = (u16*)(ws + (12ull << 20));   // 2 MB
  u16* Wob = (u16*)(ws + (14ull << 20));   // 2 MB
  u16* Qs  = (u16*)(ws + (16ull << 20));   // 8 MB  [b,h,s,d], pre-scaled
  u16* Kh  = (u16*)(ws + (24ull << 20));   // 8 MB  [b,h,s,d]
  u16* Vt  = (u16*)(ws + (32ull << 20));   // 8 MB  [b,h,d,s]
  u16* ctx = xb;                           // alias: xb dead after QKV GEMM

  cast_bf16_kernel<<<dim3(256, 5), 256, 0, stream>>>(x, Wq, Wk, Wv, Wo,
                                                     xb, Wqb, Wkb, Wvb, Wob);
  gemm_qkv_kernel<<<dim3(8, 64, 3), 256, 0, stream>>>(xb, Wqb, Wkb, Wvb,
                                                      bq, bk, bv, Qs, Kh, Vt);
  attn_kernel<<<dim3(32, 32), 256, 0, stream>>>(Qs, Kh, Vt, ctx);
  gemm_out_kernel<<<dim3(16, 64), 256, 0, stream>>>(ctx, Wob, bo, (float*)d_out);
  (void)in_sizes; (void)n_in; (void)out_size; (void)ws_size;
}